// Round 6
// baseline (551.757 us; speedup 1.0000x reference)
//
#include <hip/hip_runtime.h>
#include <stdint.h>

// Problem constants (from reference)
#define N0 409600
#define N1 40960
#define N2 4096
#define KF 10          // sampled fanout
#define IN 512
#define HID 128
#define NCLS 64

static __device__ __forceinline__ float4 f4_zero() { return make_float4(0.f, 0.f, 0.f, 0.f); }

// ---------------------------------------------------------------------------
// One self-contained 20-load burst: 5 neighbor rows x (embed lo/hi + hist
// lo/hi), SGPR base + per-lane voffset, s_waitcnt vmcnt(0) INSIDE the asm.
// All destination registers are defined by this asm -> any use is ordered
// after the waitcnt; race-free by construction (R4/R5 lesson).
// ---------------------------------------------------------------------------
#define GATHER20(E0,H0,G0,F0, E1,H1,G1,F1, E2,H2,G2,F2, E3,H3,G3,F3,         \
                 E4,H4,G4,F4, o0,o1,o2,o3,o4, be, bg)                        \
    asm volatile(                                                            \
        "global_load_dwordx4 %0, %20, %25 offset:0\n\t"                      \
        "global_load_dwordx4 %1, %20, %25 offset:16\n\t"                     \
        "global_load_dwordx4 %2, %20, %26 offset:0\n\t"                      \
        "global_load_dwordx4 %3, %20, %26 offset:16\n\t"                     \
        "global_load_dwordx4 %4, %21, %25 offset:0\n\t"                      \
        "global_load_dwordx4 %5, %21, %25 offset:16\n\t"                     \
        "global_load_dwordx4 %6, %21, %26 offset:0\n\t"                      \
        "global_load_dwordx4 %7, %21, %26 offset:16\n\t"                     \
        "global_load_dwordx4 %8, %22, %25 offset:0\n\t"                      \
        "global_load_dwordx4 %9, %22, %25 offset:16\n\t"                     \
        "global_load_dwordx4 %10, %22, %26 offset:0\n\t"                     \
        "global_load_dwordx4 %11, %22, %26 offset:16\n\t"                    \
        "global_load_dwordx4 %12, %23, %25 offset:0\n\t"                     \
        "global_load_dwordx4 %13, %23, %25 offset:16\n\t"                    \
        "global_load_dwordx4 %14, %23, %26 offset:0\n\t"                     \
        "global_load_dwordx4 %15, %23, %26 offset:16\n\t"                    \
        "global_load_dwordx4 %16, %24, %25 offset:0\n\t"                     \
        "global_load_dwordx4 %17, %24, %25 offset:16\n\t"                    \
        "global_load_dwordx4 %18, %24, %26 offset:0\n\t"                     \
        "global_load_dwordx4 %19, %24, %26 offset:16\n\t"                    \
        "s_waitcnt vmcnt(0)"                                                 \
        : "=&v"(E0), "=&v"(H0), "=&v"(G0), "=&v"(F0),                        \
          "=&v"(E1), "=&v"(H1), "=&v"(G1), "=&v"(F1),                        \
          "=&v"(E2), "=&v"(H2), "=&v"(G2), "=&v"(F2),                        \
          "=&v"(E3), "=&v"(H3), "=&v"(G3), "=&v"(F3),                        \
          "=&v"(E4), "=&v"(H4), "=&v"(G4), "=&v"(F4)                         \
        : "v"(o0), "v"(o1), "v"(o2), "v"(o3), "v"(o4), "s"(be), "s"(bg)      \
        : "memory")

// 10 independent rows, one dwordx4 each (k_block1: lane covers 4 floats).
#define GATHER10x1(d0,d1,d2,d3,d4,d5,d6,d7,d8,d9,                            \
                   o0,o1,o2,o3,o4,o5,o6,o7,o8,o9, base)                      \
    asm volatile(                                                            \
        "global_load_dwordx4 %0, %10, %20 offset:0\n\t"                      \
        "global_load_dwordx4 %1, %11, %20 offset:0\n\t"                      \
        "global_load_dwordx4 %2, %12, %20 offset:0\n\t"                      \
        "global_load_dwordx4 %3, %13, %20 offset:0\n\t"                      \
        "global_load_dwordx4 %4, %14, %20 offset:0\n\t"                      \
        "global_load_dwordx4 %5, %15, %20 offset:0\n\t"                      \
        "global_load_dwordx4 %6, %16, %20 offset:0\n\t"                      \
        "global_load_dwordx4 %7, %17, %20 offset:0\n\t"                      \
        "global_load_dwordx4 %8, %18, %20 offset:0\n\t"                      \
        "global_load_dwordx4 %9, %19, %20 offset:0\n\t"                      \
        "s_waitcnt vmcnt(0)"                                                 \
        : "=&v"(d0), "=&v"(d1), "=&v"(d2), "=&v"(d3), "=&v"(d4),             \
          "=&v"(d5), "=&v"(d6), "=&v"(d7), "=&v"(d8), "=&v"(d9)              \
        : "v"(o0), "v"(o1), "v"(o2), "v"(o3), "v"(o4),                       \
          "v"(o5), "v"(o6), "v"(o7), "v"(o8), "v"(o9), "s"(base)             \
        : "memory")

// ---------------------------------------------------------------------------
// Kernel A: pure gather/aggregate for block 0. One wave per dst node.
// No LDS, no barriers -> every resident wave issues gather bursts
// continuously for its whole lifetime. agg row -> ws.
//   agg[node] = mean_k(embed[nbr0] - h0_hist[nbr0]) + agg_h0[node]
// ---------------------------------------------------------------------------
__global__ __launch_bounds__(256) void k_gather0(
    const float* __restrict__ embed, const float* __restrict__ h0_hist,
    const float* __restrict__ agg_h0, const int* __restrict__ nbr0,
    float* __restrict__ aggbuf)
{
    const int t = threadIdx.x;
    const int wave = t >> 6;
    const int lane = t & 63;
    const int node = blockIdx.x * 4 + wave;
    const int nb = node * KF;
    const uint64_t be = (uint64_t)embed;
    const uint64_t bg = (uint64_t)h0_hist;
    const uint32_t lane_byte = (uint32_t)lane * 32u;   // lane covers 8 floats

    float4 acc0 = f4_zero(), acc1 = f4_zero();

    int idx[KF];
    #pragma unroll
    for (int j = 0; j < KF; ++j) idx[j] = nbr0[nb + j];

    #pragma unroll 1
    for (int c = 0; c < 2; ++c) {            // 2 chunks x 5 neighbors
        const uint32_t v0 = (uint32_t)idx[c * 5 + 0] * (uint32_t)(IN * 4) + lane_byte;
        const uint32_t v1 = (uint32_t)idx[c * 5 + 1] * (uint32_t)(IN * 4) + lane_byte;
        const uint32_t v2 = (uint32_t)idx[c * 5 + 2] * (uint32_t)(IN * 4) + lane_byte;
        const uint32_t v3 = (uint32_t)idx[c * 5 + 3] * (uint32_t)(IN * 4) + lane_byte;
        const uint32_t v4 = (uint32_t)idx[c * 5 + 4] * (uint32_t)(IN * 4) + lane_byte;

        float4 E0, H0, G0, F0, E1, H1, G1, F1, E2, H2, G2, F2,
               E3, H3, G3, F3, E4, H4, G4, F4;
        GATHER20(E0, H0, G0, F0, E1, H1, G1, F1, E2, H2, G2, F2,
                 E3, H3, G3, F3, E4, H4, G4, F4,
                 v0, v1, v2, v3, v4, be, bg);

        acc0.x += (E0.x + E1.x + E2.x + E3.x + E4.x) - (G0.x + G1.x + G2.x + G3.x + G4.x);
        acc0.y += (E0.y + E1.y + E2.y + E3.y + E4.y) - (G0.y + G1.y + G2.y + G3.y + G4.y);
        acc0.z += (E0.z + E1.z + E2.z + E3.z + E4.z) - (G0.z + G1.z + G2.z + G3.z + G4.z);
        acc0.w += (E0.w + E1.w + E2.w + E3.w + E4.w) - (G0.w + G1.w + G2.w + G3.w + G4.w);
        acc1.x += (H0.x + H1.x + H2.x + H3.x + H4.x) - (F0.x + F1.x + F2.x + F3.x + F4.x);
        acc1.y += (H0.y + H1.y + H2.y + H3.y + H4.y) - (F0.y + F1.y + F2.y + F3.y + F4.y);
        acc1.z += (H0.z + H1.z + H2.z + H3.z + H4.z) - (F0.z + F1.z + F2.z + F3.z + F4.z);
        acc1.w += (H0.w + H1.w + H2.w + H3.w + H4.w) - (F0.w + F1.w + F2.w + F3.w + F4.w);
    }

    const float s = 1.0f / (float)KF;
    const int col = lane * 8;
    const float4* ah = (const float4*)(agg_h0 + (size_t)node * IN + col);
    const float4 a0 = ah[0], a1 = ah[1];
    float4 r0, r1;
    r0.x = acc0.x * s + a0.x; r0.y = acc0.y * s + a0.y;
    r0.z = acc0.z * s + a0.z; r0.w = acc0.w * s + a0.w;
    r1.x = acc1.x * s + a1.x; r1.y = acc1.y * s + a1.y;
    r1.z = acc1.z * s + a1.z; r1.w = acc1.w * s + a1.w;
    *(float4*)&aggbuf[(size_t)node * IN + col]     = r0;
    *(float4*)&aggbuf[(size_t)node * IN + col + 4] = r1;
}

// ---------------------------------------------------------------------------
// Kernel B: dense for block 0 (streaming, no gather).
//   h = aggbuf @ W1 + b1 ; h1p = concat(h, relu(h)) - h1_hist
// Stage 16 agg rows to LDS (coalesced), then R2's verified GEMV verbatim.
// ---------------------------------------------------------------------------
__global__ __launch_bounds__(256) void k_dense0(
    const float* __restrict__ aggbuf, const float* __restrict__ h1_hist,
    const float* __restrict__ W1, const float* __restrict__ b1,
    float* __restrict__ h1p)
{
    __shared__ float A[16][IN];          // 32 KB
    const int t = threadIdx.x;
    const int base_node = blockIdx.x * 16;

    // stage: 2 rows per iteration, 128 threads per row, float4 each
    const int r2 = t >> 7;               // 0..1
    const int c4 = (t & 127) * 4;        // float col 0..508
    #pragma unroll
    for (int rr = 0; rr < 8; ++rr) {
        const int row = rr * 2 + r2;
        *(float4*)&A[row][c4] =
            *(const float4*)&aggbuf[(size_t)(base_node + row) * IN + c4];
    }
    __syncthreads();

    // ---- GEMV 512 -> 128 + bias + concat/relu - h1_hist (R2 verbatim) ----
    const int c0 = (t & 31) * 4;   // output col group (covers 128)
    const int rg = t >> 5;         // row group 0..7 (2 rows each -> 16)
    float4 acc[2];
    acc[0] = f4_zero(); acc[1] = f4_zero();

    #pragma unroll 4
    for (int k = 0; k < IN; ++k) {
        const float4 w = *(const float4*)&W1[k * HID + c0];
        #pragma unroll
        for (int i = 0; i < 2; ++i) {
            const float a = A[rg * 2 + i][k];
            acc[i].x += a * w.x; acc[i].y += a * w.y;
            acc[i].z += a * w.z; acc[i].w += a * w.w;
        }
    }

    const float4 bb = *(const float4*)&b1[c0];
    #pragma unroll
    for (int i = 0; i < 2; ++i) {
        const int node = base_node + rg * 2 + i;
        float4 h;
        h.x = acc[i].x + bb.x; h.y = acc[i].y + bb.y;
        h.z = acc[i].z + bb.z; h.w = acc[i].w + bb.w;
        const float4 hh0 = *(const float4*)&h1_hist[node * (2 * HID) + c0];
        const float4 hh1 = *(const float4*)&h1_hist[node * (2 * HID) + HID + c0];
        float4 o0, o1;
        o0.x = h.x - hh0.x; o0.y = h.y - hh0.y;
        o0.z = h.z - hh0.z; o0.w = h.w - hh0.w;
        o1.x = fmaxf(h.x, 0.f) - hh1.x; o1.y = fmaxf(h.y, 0.f) - hh1.y;
        o1.z = fmaxf(h.z, 0.f) - hh1.z; o1.w = fmaxf(h.w, 0.f) - hh1.w;
        *(float4*)&h1p[node * (2 * HID) + c0]       = o0;
        *(float4*)&h1p[node * (2 * HID) + HID + c0] = o1;
    }
}

// ---------------------------------------------------------------------------
// Kernel C: fused block 1 (R5 verbatim).   [8 nodes/block, 512 blocks]
//   agg = mean_k(h1p[nbr1]) + agg_h1 ; out = agg @ W2 + b2   (256 -> 64)
// ---------------------------------------------------------------------------
__global__ __launch_bounds__(256) void k_block1(
    const float* __restrict__ h1p, const float* __restrict__ agg_h1,
    const float* __restrict__ W2, const float* __restrict__ b2,
    const int* __restrict__ nbr1, float* __restrict__ out)
{
    __shared__ float B[8][2 * HID + 4];   // pad: kill bank alias on phase-2 reads
    const int t = threadIdx.x;
    const int wave = t >> 6;
    const int lane = t & 63;
    const int base_node = blockIdx.x * 8;
    const uint64_t bh = (uint64_t)h1p;
    const uint32_t lane_byte = (uint32_t)lane * 16u;   // lane covers 4 floats

    #pragma unroll 1
    for (int i = 0; i < 2; ++i) {
        const int nl = wave * 2 + i;
        const int node = base_node + nl;
        const int nb = node * KF;

        uint32_t o[KF];
        #pragma unroll
        for (int j = 0; j < KF; ++j)
            o[j] = (uint32_t)nbr1[nb + j] * (uint32_t)(2 * HID * 4) + lane_byte;

        float4 v0, v1, v2, v3, v4, v5, v6, v7, v8, v9;
        GATHER10x1(v0, v1, v2, v3, v4, v5, v6, v7, v8, v9,
                   o[0], o[1], o[2], o[3], o[4],
                   o[5], o[6], o[7], o[8], o[9], bh);

        float4 acc;
        acc.x = v0.x + v1.x + v2.x + v3.x + v4.x + v5.x + v6.x + v7.x + v8.x + v9.x;
        acc.y = v0.y + v1.y + v2.y + v3.y + v4.y + v5.y + v6.y + v7.y + v8.y + v9.y;
        acc.z = v0.z + v1.z + v2.z + v3.z + v4.z + v5.z + v6.z + v7.z + v8.z + v9.z;
        acc.w = v0.w + v1.w + v2.w + v3.w + v4.w + v5.w + v6.w + v7.w + v8.w + v9.w;

        const float s = 1.0f / (float)KF;
        const int col = lane * 4;
        const float4 g = *(const float4*)&agg_h1[(size_t)node * (2 * HID) + col];
        float4 r;
        r.x = acc.x * s + g.x; r.y = acc.y * s + g.y;
        r.z = acc.z * s + g.z; r.w = acc.w * s + g.w;
        *(float4*)&B[nl][col] = r;
    }
    __syncthreads();

    // ---- phase 2: GEMV 256 -> 64 + bias ----
    const int r = t >> 5;          // node row 0..7
    const int c0 = (t & 31) * 2;   // col pair (covers 64)
    float2 acc = make_float2(0.f, 0.f);
    #pragma unroll 4
    for (int k = 0; k < 2 * HID; ++k) {
        const float a = B[r][k];
        const float2 w = *(const float2*)&W2[k * NCLS + c0];
        acc.x += a * w.x; acc.y += a * w.y;
    }
    const float2 bb = *(const float2*)&b2[c0];
    float2 o;
    o.x = acc.x + bb.x; o.y = acc.y + bb.y;
    const int node = base_node + r;
    *(float2*)&out[node * NCLS + c0] = o;
}

extern "C" void kernel_launch(void* const* d_in, const int* in_sizes, int n_in,
                              void* d_out, int out_size, void* d_ws, size_t ws_size,
                              hipStream_t stream) {
    const float* embed   = (const float*)d_in[0];
    const float* h0_hist = (const float*)d_in[1];
    const float* h1_hist = (const float*)d_in[2];
    const float* agg_h0  = (const float*)d_in[3];
    const float* agg_h1  = (const float*)d_in[4];
    const float* W1      = (const float*)d_in[5];
    const float* b1      = (const float*)d_in[6];
    const float* W2      = (const float*)d_in[7];
    const float* b2      = (const float*)d_in[8];
    const int*   nbr0    = (const int*)d_in[9];
    const int*   nbr1    = (const int*)d_in[10];
    float* out = (float*)d_out;

    // ws layout: aggbuf [N1, 512] f32 = 83.9 MB, then h1p [N1, 256] f32 = 41.9 MB
    float* aggbuf = (float*)d_ws;
    float* h1p    = aggbuf + (size_t)N1 * IN;

    k_gather0<<<N1 / 4, 256, 0, stream>>>(embed, h0_hist, agg_h0, nbr0, aggbuf);
    k_dense0<<<N1 / 16, 256, 0, stream>>>(aggbuf, h1_hist, W1, b1, h1p);
    k_block1<<<N2 / 8, 256, 0, stream>>>(h1p, agg_h1, W2, b2, nbr1, out);
}